// Round 1
// baseline (754.714 us; speedup 1.0000x reference)
//
#include <hip/hip_runtime.h>
#include <math.h>

// Problem constants: B=8, C=64, H=W=256, WIN=8, NH=NW=32, P=64.
// Key identity: ifft(fft(out1)+fft(out2)).real+imag == out1+out2 (FFT is a no-op).
// roll(-4) on input and roll(+4) on output fuse into addressing: h=(wh*8+i+4)&255.

// XOR-swizzled LDS layout for 64x64 tiles: element (r,p) at r*64 + 4*((p/4)^(r/4)) + p%4.
// All inner-loop b128 reads are 2-way-or-broadcast (free); 16B aligned.
__device__ __forceinline__ int idxf(int r, int g) {
    return (r << 6) + (((g ^ (r >> 2)) & 15) << 2);
}
__device__ __forceinline__ int idx1(int r, int p) {
    return idxf(r, p >> 2) + (p & 3);
}

// acc[i*4+p] += sum_k Wt[k][ig*4+i] * X[k][pg*4+p]   (k over 64) -- conv1x1 / proj
__device__ __forceinline__ void mm_tn(const float* Wt, const float* X, int ig, int pg, float acc[16]) {
#pragma unroll 2
    for (int g = 0; g < 16; ++g) {
        float4 w[4], x[4];
#pragma unroll
        for (int j = 0; j < 4; ++j) {
            w[j] = *(const float4*)&Wt[idxf(g * 4 + j, ig)];
            x[j] = *(const float4*)&X[idxf(g * 4 + j, pg)];
        }
#pragma unroll
        for (int j = 0; j < 4; ++j) {
            acc[0] += w[j].x * x[j].x;  acc[1] += w[j].x * x[j].y;  acc[2] += w[j].x * x[j].z;  acc[3] += w[j].x * x[j].w;
            acc[4] += w[j].y * x[j].x;  acc[5] += w[j].y * x[j].y;  acc[6] += w[j].y * x[j].z;  acc[7] += w[j].y * x[j].w;
            acc[8] += w[j].z * x[j].x;  acc[9] += w[j].z * x[j].y;  acc[10] += w[j].z * x[j].z; acc[11] += w[j].z * x[j].w;
            acc[12] += w[j].w * x[j].x; acc[13] += w[j].w * x[j].y; acc[14] += w[j].w * x[j].z; acc[15] += w[j].w * x[j].w;
        }
    }
}

// acc[i*4+j] += sum_p A[ig*4+i][p] * Bm[jg*4+j][p]   -- S = kn . qn^T / kn . V^T
__device__ __forceinline__ void mm_nt(const float* A, const float* Bm, int ig, int jg, float acc[16]) {
#pragma unroll 2
    for (int g = 0; g < 16; ++g) {
        float4 a[4], bb[4];
#pragma unroll
        for (int i = 0; i < 4; ++i) a[i] = *(const float4*)&A[idxf(ig * 4 + i, g)];
#pragma unroll
        for (int j = 0; j < 4; ++j) bb[j] = *(const float4*)&Bm[idxf(jg * 4 + j, g)];
#pragma unroll
        for (int i = 0; i < 4; ++i)
#pragma unroll
            for (int j = 0; j < 4; ++j)
                acc[i * 4 + j] += a[i].x * bb[j].x + a[i].y * bb[j].y + a[i].z * bb[j].z + a[i].w * bb[j].w;
    }
}

// acc[i*4+p] += sum_d E[ig*4+i][d] * M[d][pg*4+p]   -- out = A . V / A . qn
__device__ __forceinline__ void mm_nn(const float* E, const float* M, int ig, int pg, float acc[16]) {
#pragma unroll 2
    for (int g = 0; g < 16; ++g) {
        float4 e[4], m[4];
#pragma unroll
        for (int i = 0; i < 4; ++i) e[i] = *(const float4*)&E[idxf(ig * 4 + i, g)];
#pragma unroll
        for (int j = 0; j < 4; ++j) m[j] = *(const float4*)&M[idxf(g * 4 + j, pg)];
#pragma unroll
        for (int i = 0; i < 4; ++i) {
            acc[i * 4 + 0] += e[i].x * m[0].x + e[i].y * m[1].x + e[i].z * m[2].x + e[i].w * m[3].x;
            acc[i * 4 + 1] += e[i].x * m[0].y + e[i].y * m[1].y + e[i].z * m[2].y + e[i].w * m[3].y;
            acc[i * 4 + 2] += e[i].x * m[0].z + e[i].y * m[1].z + e[i].z * m[2].z + e[i].w * m[3].z;
            acc[i * 4 + 3] += e[i].x * m[0].w + e[i].y * m[1].w + e[i].z * m[2].w + e[i].w * m[3].w;
        }
    }
}

// depthwise 3x3, zero-padded within the 8x8 window. T = t[p][o] (post-conv1x1), Out[o][p].
__device__ __forceinline__ void dw_apply(const float* T, float* Out, const float* __restrict__ dww,
                                         int half, int tid) {
    int o = tid & 63;
    int pq = tid >> 6;
    const float* wp = dww + (half * 64 + o) * 9;
    float wq[9];
#pragma unroll
    for (int k = 0; k < 9; ++k) wq[k] = wp[k];
#pragma unroll
    for (int k = 0; k < 16; ++k) {
        int p = pq * 16 + k;
        int pi = p >> 3, pj = p & 7;
        float a = 0.f;
#pragma unroll
        for (int dy = 0; dy < 3; ++dy) {
            int y = pi + dy - 1;
            if (y >= 0 && y < 8) {
#pragma unroll
                for (int dx = 0; dx < 3; ++dx) {
                    int xx = pj + dx - 1;
                    if (xx >= 0 && xx < 8) a += wq[dy * 3 + dx] * T[idx1(y * 8 + xx, o)];
                }
            }
        }
        Out[idx1(o, p)] = a;
    }
}

// softmax over columns of each row of S (64x64, in place), with pre-scale.
// Leaves UNNORMALIZED exp in S; row 1/sum in rinv[64]. Caller folds rinv into output rows.
__device__ __forceinline__ void softmax_ip(float* S, float* red, float* rmax, float* rinv,
                                           float scale, int tid) {
    int r = tid & 63, q = tid >> 6;
    float m = -3.4e38f;
#pragma unroll
    for (int k = 0; k < 16; ++k) m = fmaxf(m, S[idx1(r, q * 16 + k)] * scale);
    red[q * 64 + r] = m;
    __syncthreads();
    if (tid < 64)
        rmax[tid] = fmaxf(fmaxf(red[tid], red[64 + tid]), fmaxf(red[128 + tid], red[192 + tid]));
    __syncthreads();
    float mm = rmax[r];
    float s = 0.f;
#pragma unroll
    for (int k = 0; k < 16; ++k) {
        int id = idx1(r, q * 16 + k);
        float e = __expf(S[id] * scale - mm);
        S[id] = e;
        s += e;
    }
    red[q * 64 + r] = s;
    __syncthreads();
    if (tid < 64)
        rinv[tid] = 1.0f / (red[tid] + red[64 + tid] + red[128 + tid] + red[192 + tid]);
    __syncthreads();
}

__global__ void qn_kernel(const float* __restrict__ q, float* __restrict__ qn) {
    int row = blockIdx.x;   // b*64 + c
    int p = threadIdx.x;    // 0..63
    float v = q[row * 64 + p];
    float s = v * v;
#pragma unroll
    for (int off = 32; off > 0; off >>= 1) s += __shfl_xor(s, off, 64);
    float inv = 1.0f / fmaxf(sqrtf(s), 1e-12f);
    qn[row * 64 + p] = v * inv;
}

__global__ void __launch_bounds__(256, 2)
attn_main(const float* __restrict__ xg, const float* __restrict__ qn_g,
          const float* __restrict__ kvw, const float* __restrict__ dww,
          const float* __restrict__ pjw, const float* __restrict__ rs1p,
          const float* __restrict__ rs2p, float* __restrict__ outg) {
    __shared__ float bufA[4096];  // x window -> qn
    __shared__ float bufT[4096];  // t -> S/E -> O
    __shared__ float bufK[4096];  // kn -> pwT
    __shared__ float bufV[4096];  // wT_K -> wT_V -> v
    __shared__ float red[256];
    __shared__ float rstat[64];
    __shared__ float rinv1[64];
    __shared__ float rinv2[64];

    const int tid = threadIdx.x;
    // XCD swizzle: batch b = blockIdx&7 -> each batch pinned to one XCD (8 XCDs, round-robin
    // dispatch). Neighboring ww windows (adjacent 32B chunks of the same cache line) share an L2.
    const int b = blockIdx.x & 7;
    const int widx = blockIdx.x >> 3;
    const int wh = widx >> 5;
    const int ww = widx & 31;

    const float rs1 = rs1p[0];
    const float rs2 = rs2p[0];

    // ---- 1. load rolled x window into bufA; stage kv_w K-half transposed into bufV
#pragma unroll
    for (int rep = 0; rep < 2; ++rep) {
        int r = tid + rep * 256;
        int c = r >> 3, i = r & 7;
        int h = (wh * 8 + i + 4) & 255;
        const float* src = xg + (((b * 64 + c) * 256 + h) << 8);
        int w0 = ww * 8 + 4;              // <= 252, 16B aligned
        int w1 = (ww * 8 + 8) & 255;      // wraps to 0 only at ww=31
        float4 av = *(const float4*)(src + w0);
        float4 bv = *(const float4*)(src + w1);
        *(float4*)&bufA[idxf(c, i * 2)] = av;
        *(float4*)&bufA[idxf(c, i * 2 + 1)] = bv;
    }
#pragma unroll
    for (int rep = 0; rep < 4; ++rep) {
        int e4 = tid + rep * 256;
        int o = e4 >> 4, cg = e4 & 15;
        float4 w = *(const float4*)(kvw + e4 * 4);
        bufV[idx1(cg * 4 + 0, o)] = w.x;
        bufV[idx1(cg * 4 + 1, o)] = w.y;
        bufV[idx1(cg * 4 + 2, o)] = w.z;
        bufV[idx1(cg * 4 + 3, o)] = w.w;
    }
    __syncthreads();

    // ---- 2. conv1x1 K-half: t[p][o] = sum_c wK[o][c] * x[c][p]
    {
        int og = tid & 15, pg = tid >> 4;
        float acc[16] = {};
        mm_tn(bufV, bufA, og, pg, acc);
#pragma unroll
        for (int pp = 0; pp < 4; ++pp)
            *(float4*)&bufT[idxf(pg * 4 + pp, og)] =
                make_float4(acc[pp], acc[4 + pp], acc[8 + pp], acc[12 + pp]);
    }
    __syncthreads();

    // ---- 3. dwconv K -> bufK (raw); stage kv_w V-half transposed into bufV
    dw_apply(bufT, bufK, dww, 0, tid);
#pragma unroll
    for (int rep = 0; rep < 4; ++rep) {
        int e4 = tid + rep * 256;
        int o = e4 >> 4, cg = e4 & 15;
        float4 w = *(const float4*)(kvw + 4096 + e4 * 4);
        bufV[idx1(cg * 4 + 0, o)] = w.x;
        bufV[idx1(cg * 4 + 1, o)] = w.y;
        bufV[idx1(cg * 4 + 2, o)] = w.z;
        bufV[idx1(cg * 4 + 3, o)] = w.w;
    }
    __syncthreads();

    // ---- 4. row sumsq of K (for l2norm); conv1x1 V-half into bufT
    {
        int r = tid & 63, q = tid >> 6;
        float s = 0.f;
#pragma unroll
        for (int k = 0; k < 16; ++k) {
            float v = bufK[idx1(r, q * 16 + k)];
            s += v * v;
        }
        red[q * 64 + r] = s;
    }
    {
        int og = tid & 15, pg = tid >> 4;
        float acc[16] = {};
        mm_tn(bufV, bufA, og, pg, acc);
#pragma unroll
        for (int pp = 0; pp < 4; ++pp)
            *(float4*)&bufT[idxf(pg * 4 + pp, og)] =
                make_float4(acc[pp], acc[4 + pp], acc[8 + pp], acc[12 + pp]);
    }
    __syncthreads();
    if (tid < 64) {
        float s = red[tid] + red[64 + tid] + red[128 + tid] + red[192 + tid];
        rstat[tid] = 1.0f / fmaxf(sqrtf(s), 1e-12f);
    }
    __syncthreads();

    // ---- 5. normalize kn rows in place; load qn into bufA (x window is dead)
    {
        int r = tid & 63, q = tid >> 6;
        float inv = rstat[r];
#pragma unroll
        for (int k = 0; k < 16; ++k) bufK[idx1(r, q * 16 + k)] *= inv;
    }
#pragma unroll
    for (int rep = 0; rep < 4; ++rep) {
        int e4 = tid + rep * 256;
        int d = e4 >> 4, pgm = e4 & 15;
        *(float4*)&bufA[idxf(d, pgm)] = *(const float4*)(qn_g + b * 4096 + e4 * 4);
    }
    __syncthreads();

    // ---- 6. dwconv V -> bufV (overwrites staged weights; conv-V already consumed them)
    dw_apply(bufT, bufV, dww, 1, tid);
    __syncthreads();

    const int cg = tid & 15, pg = tid >> 4;

    // ---- 7. S1 = kn . qn^T -> bufT; softmax
    {
        float s[16] = {};
        mm_nt(bufK, bufA, cg, pg, s);
#pragma unroll
        for (int i = 0; i < 4; ++i)
            *(float4*)&bufT[idxf(cg * 4 + i, pg)] =
                make_float4(s[i * 4], s[i * 4 + 1], s[i * 4 + 2], s[i * 4 + 3]);
    }
    __syncthreads();
    softmax_ip(bufT, red, rstat, rinv1, rs1, tid);

    // ---- 8. out1 = A1 . V (rows scaled by rinv1)
    float o1[16] = {};
    mm_nn(bufT, bufV, cg, pg, o1);
#pragma unroll
    for (int i = 0; i < 4; ++i) {
        float r1 = rinv1[cg * 4 + i];
        o1[i * 4 + 0] *= r1; o1[i * 4 + 1] *= r1; o1[i * 4 + 2] *= r1; o1[i * 4 + 3] *= r1;
    }
    __syncthreads();

    // ---- 9. S2 = kn . V^T -> bufT; softmax
    {
        float s[16] = {};
        mm_nt(bufK, bufV, cg, pg, s);
#pragma unroll
        for (int i = 0; i < 4; ++i)
            *(float4*)&bufT[idxf(cg * 4 + i, pg)] =
                make_float4(s[i * 4], s[i * 4 + 1], s[i * 4 + 2], s[i * 4 + 3]);
    }
    __syncthreads();
    softmax_ip(bufT, red, rstat, rinv2, rs2, tid);

    // ---- 10. out2 = A2 . qn; combine O = out1 + rinv2*out2
    {
        float o2[16] = {};
        mm_nn(bufT, bufA, cg, pg, o2);
#pragma unroll
        for (int i = 0; i < 4; ++i) {
            float r2 = rinv2[cg * 4 + i];
            o1[i * 4 + 0] += r2 * o2[i * 4 + 0];
            o1[i * 4 + 1] += r2 * o2[i * 4 + 1];
            o1[i * 4 + 2] += r2 * o2[i * 4 + 2];
            o1[i * 4 + 3] += r2 * o2[i * 4 + 3];
        }
    }
    __syncthreads();

    // ---- 11. O -> bufT; stage proj_w transposed into bufK (kn is dead)
#pragma unroll
    for (int i = 0; i < 4; ++i)
        *(float4*)&bufT[idxf(cg * 4 + i, pg)] =
            make_float4(o1[i * 4], o1[i * 4 + 1], o1[i * 4 + 2], o1[i * 4 + 3]);
#pragma unroll
    for (int rep = 0; rep < 4; ++rep) {
        int e4 = tid + rep * 256;
        int co = e4 >> 4, cig = e4 & 15;
        float4 w = *(const float4*)(pjw + e4 * 4);
        bufK[idx1(cig * 4 + 0, co)] = w.x;
        bufK[idx1(cig * 4 + 1, co)] = w.y;
        bufK[idx1(cig * 4 + 2, co)] = w.z;
        bufK[idx1(cig * 4 + 3, co)] = w.w;
    }
    __syncthreads();

    // ---- 12. proj + scatter store with roll(+4) fused
    {
        float pa[16] = {};
        mm_tn(bufK, bufT, cg, pg, pa);
        int hi = pg >> 1;
        int j0 = (pg & 1) << 2;
        int h = (wh * 8 + hi + 4) & 255;
        int w0 = (ww * 8 + 4 + j0) & 255;  // multiple of 4, never crosses the row end
#pragma unroll
        for (int i = 0; i < 4; ++i) {
            int c = cg * 4 + i;
            *(float4*)(outg + (((b * 64 + c) * 256 + h) << 8) + w0) =
                make_float4(pa[i * 4], pa[i * 4 + 1], pa[i * 4 + 2], pa[i * 4 + 3]);
        }
    }
}

extern "C" void kernel_launch(void* const* d_in, const int* in_sizes, int n_in,
                              void* d_out, int out_size, void* d_ws, size_t ws_size,
                              hipStream_t stream) {
    const float* x = (const float*)d_in[0];
    const float* q = (const float*)d_in[1];
    const float* kvw = (const float*)d_in[2];
    const float* dww = (const float*)d_in[3];
    const float* pjw = (const float*)d_in[4];
    const float* rs1 = (const float*)d_in[5];
    const float* rs2 = (const float*)d_in[6];
    float* out = (float*)d_out;
    float* qn = (float*)d_ws;  // 8*64*64 floats = 128 KB scratch

    qn_kernel<<<dim3(512), dim3(64), 0, stream>>>(q, qn);
    attn_main<<<dim3(8192), dim3(256), 0, stream>>>(x, qn, kvw, dww, pjw, rs1, rs2, out);
}

// Round 2
// 408.834 us; speedup vs baseline: 1.8460x; 1.8460x over previous
//
#include <hip/hip_runtime.h>
#include <math.h>

// B=8, C=64, H=W=256, WIN=8, NH=NW=32, P=64.
// FFT identity: ifft(fft(out1)+fft(out2)).real+imag == out1+out2.
// roll(-4)/roll(+4) fused into addressing: h=(wh*8+i+4)&255.
// All 7 matmuls -> mfma_f32_16x16x32_bf16 (fp32 accum). Softmax in-register on C-frags.
// Weights/qn read as fragments directly from global (L2-hot), LDS holds only bf16 tiles.

typedef __attribute__((ext_vector_type(8))) short short8;
typedef __attribute__((ext_vector_type(4))) float f32x4;

#define LSTR 72  // bf16 row stride: 144B = 9 x 16B chunks -> odd chunk stride, banks spread

__device__ __forceinline__ short f2bf(float f) {  // RNE float->bf16
    unsigned u = __float_as_uint(f);
    u = u + 0x7FFFu + ((u >> 16) & 1u);
    return (short)(u >> 16);
}
__device__ __forceinline__ void unpack8(short8 h, float* f) {
#pragma unroll
    for (int j = 0; j < 8; ++j) f[j] = __uint_as_float(((unsigned)(unsigned short)h[j]) << 16);
}

__global__ void prep(const float* __restrict__ q, const float* __restrict__ kvw,
                     const float* __restrict__ pjw, short* __restrict__ qn_dp,
                     short* __restrict__ qn_pd, short* __restrict__ kvw_bf,
                     short* __restrict__ pjw_bf) {
    int bid = blockIdx.x, t = threadIdx.x;
    if (bid < 512) {                       // qn rows: b*64+d, l2norm over P=64
        float v = q[bid * 64 + t];
        float s = v * v;
#pragma unroll
        for (int off = 32; off > 0; off >>= 1) s += __shfl_xor(s, off, 64);
        float inv = 1.0f / fmaxf(sqrtf(s), 1e-12f);
        short h = f2bf(v * inv);
        int b = bid >> 6, d = bid & 63;
        qn_dp[b * 4096 + d * 64 + t] = h;  // [b][d][p]
        qn_pd[b * 4096 + t * 64 + d] = h;  // [b][p][d]
    } else {
        int idx = (bid - 512) * 64 + t;
        if (idx < 8192) kvw_bf[idx] = f2bf(kvw[idx]);
        else if (idx < 12288) pjw_bf[idx - 8192] = f2bf(pjw[idx - 8192]);
    }
}

__global__ void __launch_bounds__(256, 2)
attn_main(const float* __restrict__ xg, const short* __restrict__ qn_dp,
          const short* __restrict__ qn_pd, const short* __restrict__ kvw_bf,
          const float* __restrict__ dww, const short* __restrict__ pjw_bf,
          const float* __restrict__ rs1p, const float* __restrict__ rs2p,
          float* __restrict__ outg) {
    __shared__ short Xs[64 * LSTR];   // x window [p][c-swz]; later O [p][ci-swz]
    __shared__ short Ts[64 * LSTR];   // conv1x1 result [o][p] (per half)
    __shared__ short KNs[64 * LSTR];  // kn [c][p]
    __shared__ short Vs[64 * LSTR];   // v  [d][p]
    __shared__ short VTs[64 * LSTR];  // v^T [p][d-swz]
    __shared__ short A1s[64 * LSTR];  // attn probs [c][d] (A1 then A2)

    const int tid = threadIdx.x;
    const int w = tid >> 6, lane = tid & 63, lg = lane >> 4, ln = lane & 15;
    const int b = blockIdx.x & 7;            // batch -> XCD pinning
    const int widx = blockIdx.x >> 3;
    const int wh = widx >> 5, ww = widx & 31;
    const float rs1 = rs1p[0], rs2 = rs2p[0];

    // Prefetch qn fragments (B-operands for S1 / out2) from global (L2-hot).
    const short* qdp = qn_dp + b * 4096;
    const short* qpd = qn_pd + b * 4096;
    short8 fq1[8], fq2[8];
#pragma unroll
    for (int t = 0; t < 4; ++t)
#pragma unroll
        for (int kc = 0; kc < 2; ++kc) {
            fq1[t * 2 + kc] = *(const short8*)(qdp + (t * 16 + ln) * 64 + kc * 32 + lg * 8);
            fq2[t * 2 + kc] = *(const short8*)(qpd + (t * 16 + ln) * 64 + kc * 32 + lg * 8);
        }

    // ---- stage x window (rolled) into Xs[p][c-swz] bf16
#pragma unroll
    for (int rep = 0; rep < 2; ++rep) {
        int r = tid + rep * 256;
        int c = r >> 3, i = r & 7;
        int h = (wh * 8 + i + 4) & 255;
        const float* src = xg + (((b * 64 + c) * 256 + h) << 8);
        float4 av = *(const float4*)(src + ww * 8 + 4);
        float4 bv = *(const float4*)(src + ((ww * 8 + 8) & 255));
        float vals[8] = {av.x, av.y, av.z, av.w, bv.x, bv.y, bv.z, bv.w};
        int csw = ((((c >> 3) ^ i) & 7) << 3) | (c & 7);  // i == p>>3 for all 8 writes
#pragma unroll
        for (int j = 0; j < 8; ++j) Xs[(i * 8 + j) * LSTR + csw] = f2bf(vals[j]);
    }
    __syncthreads();

    // ================= conv1x1 + dwconv, K half then V half =================
#pragma unroll 1
    for (int half = 0; half < 2; ++half) {
        // conv1x1: T[o][p] = sum_c W[o][c] X[c][p]; A=W from global, B=X from LDS
        {
            f32x4 acc[4] = {};
            const short* Wg = kvw_bf + half * 4096;
#pragma unroll
            for (int kc = 0; kc < 2; ++kc) {
                short8 af = *(const short8*)(Wg + (w * 16 + ln) * 64 + kc * 32 + lg * 8);
#pragma unroll
                for (int t = 0; t < 4; ++t) {
                    int row = t * 16 + ln;
                    short8 bf = *(const short8*)&Xs[row * LSTR + ((((kc * 4 + lg) ^ (row >> 3)) & 7) << 3)];
                    acc[t] = __builtin_amdgcn_mfma_f32_16x16x32_bf16(af, bf, acc[t], 0, 0, 0);
                }
            }
#pragma unroll
            for (int t = 0; t < 4; ++t)
#pragma unroll
                for (int r = 0; r < 4; ++r)
                    Ts[(w * 16 + lg * 4 + r) * LSTR + t * 16 + ln] = f2bf(acc[t][r]);
        }
        __syncthreads();

        // dwconv 3x3 zero-padded in window; thread: channel o = tid>>2, rows 2q,2q+1
        {
            int o = tid >> 2, q = tid & 3;
            const float* wp = dww + (half * 64 + o) * 9;
            float wq[9];
#pragma unroll
            for (int k = 0; k < 9; ++k) wq[k] = wp[k];
            float rv[4][8];
#pragma unroll
            for (int dy = 0; dy < 4; ++dy) {
                int y = 2 * q - 1 + dy;
                if (y >= 0 && y < 8) {
                    short8 t8 = *(const short8*)&Ts[o * LSTR + y * 8];
                    unpack8(t8, rv[dy]);
                } else {
#pragma unroll
                    for (int j = 0; j < 8; ++j) rv[dy][j] = 0.f;
                }
            }
            float ov[16];
#pragma unroll
            for (int rr = 0; rr < 2; ++rr)
#pragma unroll
                for (int j = 0; j < 8; ++j) {
                    float a = 0.f;
#pragma unroll
                    for (int dy = 0; dy < 3; ++dy)
#pragma unroll
                        for (int dx = 0; dx < 3; ++dx) {
                            int xx = j + dx - 1;
                            if (xx >= 0 && xx < 8) a += wq[dy * 3 + dx] * rv[rr + dy][xx];
                        }
                    ov[rr * 8 + j] = a;
                }
            if (half == 0) {  // K: l2norm rows then kn -> KNs[c][p]
                float ss = 0.f;
#pragma unroll
                for (int k = 0; k < 16; ++k) ss += ov[k] * ov[k];
                ss += __shfl_xor(ss, 1);
                ss += __shfl_xor(ss, 2);
                float inv = 1.0f / fmaxf(sqrtf(ss), 1e-12f);
                short8 h0, h1;
#pragma unroll
                for (int k = 0; k < 8; ++k) { h0[k] = f2bf(ov[k] * inv); h1[k] = f2bf(ov[k + 8] * inv); }
                *(short8*)&KNs[o * LSTR + q * 16] = h0;
                *(short8*)&KNs[o * LSTR + q * 16 + 8] = h1;
            } else {          // V: Vs[d][p] + transposed VTs[p][d-swz]
                short8 h0, h1;
#pragma unroll
                for (int k = 0; k < 8; ++k) { h0[k] = f2bf(ov[k]); h1[k] = f2bf(ov[k + 8]); }
                *(short8*)&Vs[o * LSTR + q * 16] = h0;
                *(short8*)&Vs[o * LSTR + q * 16 + 8] = h1;
#pragma unroll
                for (int k = 0; k < 16; ++k) {
                    int p = q * 16 + k;
                    int csw = ((((o >> 3) ^ (p >> 3)) & 7) << 3) | (o & 7);
                    VTs[p * LSTR + csw] = (k < 8) ? h0[k] : h1[k - 8];
                }
            }
        }
        __syncthreads();
    }

    const int arow = (w * 16 + ln) * LSTR;       // A-frag row base (m = w*16+ln)
    const int crow = w * 16 + lg * 4;            // C-frag row base

    // ================= S1 = kn . qn^T ; softmax in-register -> A1s =================
    {
        f32x4 s1[4] = {};
#pragma unroll
        for (int kc = 0; kc < 2; ++kc) {
            short8 af = *(const short8*)&KNs[arow + kc * 32 + lg * 8];
#pragma unroll
            for (int t = 0; t < 4; ++t)
                s1[t] = __builtin_amdgcn_mfma_f32_16x16x32_bf16(af, fq1[t * 2 + kc], s1[t], 0, 0, 0);
        }
#pragma unroll
        for (int r = 0; r < 4; ++r) {
            float v0 = s1[0][r] * rs1, v1 = s1[1][r] * rs1, v2 = s1[2][r] * rs1, v3 = s1[3][r] * rs1;
            float m = fmaxf(fmaxf(v0, v1), fmaxf(v2, v3));
#pragma unroll
            for (int off = 1; off < 16; off <<= 1) m = fmaxf(m, __shfl_xor(m, off));
            float e0 = __expf(v0 - m), e1 = __expf(v1 - m), e2 = __expf(v2 - m), e3 = __expf(v3 - m);
            float s = e0 + e1 + e2 + e3;
#pragma unroll
            for (int off = 1; off < 16; off <<= 1) s += __shfl_xor(s, off);
            float inv = 1.0f / s;
            A1s[(crow + r) * LSTR + 0 * 16 + ln] = f2bf(e0 * inv);
            A1s[(crow + r) * LSTR + 1 * 16 + ln] = f2bf(e1 * inv);
            A1s[(crow + r) * LSTR + 2 * 16 + ln] = f2bf(e2 * inv);
            A1s[(crow + r) * LSTR + 3 * 16 + ln] = f2bf(e3 * inv);
        }
    }
    __syncthreads();

    // ================= out1 = A1 . V  ;  S2 = kn . V^T =================
    f32x4 o1[4] = {};
    f32x4 s2[4] = {};
    {
#pragma unroll
        for (int kc = 0; kc < 2; ++kc) {
            short8 af = *(const short8*)&A1s[arow + kc * 32 + lg * 8];
#pragma unroll
            for (int t = 0; t < 4; ++t) {
                int row = t * 16 + ln;
                short8 bf = *(const short8*)&VTs[row * LSTR + ((((kc * 4 + lg) ^ (row >> 3)) & 7) << 3)];
                o1[t] = __builtin_amdgcn_mfma_f32_16x16x32_bf16(af, bf, o1[t], 0, 0, 0);
            }
        }
#pragma unroll
        for (int kc = 0; kc < 2; ++kc) {
            short8 af = *(const short8*)&KNs[arow + kc * 32 + lg * 8];
#pragma unroll
            for (int t = 0; t < 4; ++t) {
                short8 bf = *(const short8*)&Vs[(t * 16 + ln) * LSTR + kc * 32 + lg * 8];
                s2[t] = __builtin_amdgcn_mfma_f32_16x16x32_bf16(af, bf, s2[t], 0, 0, 0);
            }
        }
    }
    __syncthreads();  // all A1 reads done -> A1s reusable for A2

    // softmax(S2) -> A2 (into A1s)
#pragma unroll
    for (int r = 0; r < 4; ++r) {
        float v0 = s2[0][r] * rs2, v1 = s2[1][r] * rs2, v2 = s2[2][r] * rs2, v3 = s2[3][r] * rs2;
        float m = fmaxf(fmaxf(v0, v1), fmaxf(v2, v3));
#pragma unroll
        for (int off = 1; off < 16; off <<= 1) m = fmaxf(m, __shfl_xor(m, off));
        float e0 = __expf(v0 - m), e1 = __expf(v1 - m), e2 = __expf(v2 - m), e3 = __expf(v3 - m);
        float s = e0 + e1 + e2 + e3;
#pragma unroll
        for (int off = 1; off < 16; off <<= 1) s += __shfl_xor(s, off);
        float inv = 1.0f / s;
        A1s[(crow + r) * LSTR + 0 * 16 + ln] = f2bf(e0 * inv);
        A1s[(crow + r) * LSTR + 1 * 16 + ln] = f2bf(e1 * inv);
        A1s[(crow + r) * LSTR + 2 * 16 + ln] = f2bf(e2 * inv);
        A1s[(crow + r) * LSTR + 3 * 16 + ln] = f2bf(e3 * inv);
    }
    __syncthreads();

    // ================= out2 = A2 . qn, accumulate into o1; O -> Xs[p][ci-swz] =================
    {
#pragma unroll
        for (int kc = 0; kc < 2; ++kc) {
            short8 af = *(const short8*)&A1s[arow + kc * 32 + lg * 8];
#pragma unroll
            for (int t = 0; t < 4; ++t)
                o1[t] = __builtin_amdgcn_mfma_f32_16x16x32_bf16(af, fq2[t * 2 + kc], o1[t], 0, 0, 0);
        }
#pragma unroll
        for (int t = 0; t < 4; ++t)
#pragma unroll
            for (int r = 0; r < 4; ++r) {
                int c = crow + r, p = t * 16 + ln;
                int csw = ((((c >> 3) ^ (p >> 3)) & 7) << 3) | (c & 7);
                Xs[p * LSTR + csw] = f2bf(o1[t][r]);
            }
    }
    __syncthreads();

    // ================= proj + scatter store (roll +4 fused) =================
    {
        f32x4 pr[4] = {};
#pragma unroll
        for (int kc = 0; kc < 2; ++kc) {
            short8 af = *(const short8*)(pjw_bf + (w * 16 + ln) * 64 + kc * 32 + lg * 8);
#pragma unroll
            for (int t = 0; t < 4; ++t) {
                int row = t * 16 + ln;
                short8 bf = *(const short8*)&Xs[row * LSTR + ((((kc * 4 + lg) ^ (row >> 3)) & 7) << 3)];
                pr[t] = __builtin_amdgcn_mfma_f32_16x16x32_bf16(af, bf, pr[t], 0, 0, 0);
            }
        }
#pragma unroll
        for (int t = 0; t < 4; ++t)
#pragma unroll
            for (int r = 0; r < 4; ++r) {
                int co = crow + r, p = t * 16 + ln;
                int h = (wh * 8 + (p >> 3) + 4) & 255;
                int wc = (ww * 8 + (p & 7) + 4) & 255;
                outg[((b * 64 + co) << 16) + (h << 8) + wc] = pr[t][r];
            }
    }
}

extern "C" void kernel_launch(void* const* d_in, const int* in_sizes, int n_in,
                              void* d_out, int out_size, void* d_ws, size_t ws_size,
                              hipStream_t stream) {
    const float* x = (const float*)d_in[0];
    const float* q = (const float*)d_in[1];
    const float* kvw = (const float*)d_in[2];
    const float* dww = (const float*)d_in[3];
    const float* pjw = (const float*)d_in[4];
    const float* rs1 = (const float*)d_in[5];
    const float* rs2 = (const float*)d_in[6];
    float* out = (float*)d_out;

    short* ws = (short*)d_ws;
    short* qn_dp = ws;                 // 8*4096 bf16
    short* qn_pd = ws + 32768;         // 8*4096 bf16
    short* kvw_bf = ws + 65536;        // 8192 bf16
    short* pjw_bf = ws + 73728;        // 4096 bf16

    prep<<<dim3(704), dim3(64), 0, stream>>>(q, kvw, pjw, qn_dp, qn_pd, kvw_bf, pjw_bf);
    attn_main<<<dim3(8192), dim3(256), 0, stream>>>(x, qn_dp, qn_pd, kvw_bf, dww, pjw_bf,
                                                    rs1, rs2, out);
}